// Round 3
// baseline (242.067 us; speedup 1.0000x reference)
//
#include <hip/hip_runtime.h>

#define R_    512
#define K_    17
#define HIN   56
#define WIN   56
#define OUTS  96
#define NMAP  (R_ * K_)
#define NT    384     // 6 waves/block
#define GRID  1088    // persistent-ish: each block pipelines ITERS map-pairs
#define ITERS 4       // 1088*4 = 4352 = NMAP/2 pairs
#define RST   98      // tmp row stride in v2f units (784 B: 16B-aligned, banks stagger by 4)
#define TROWS 60      // phys rows: 0,1 = pad(row0); 2..57 = rows 0..55; 58,59 = pad(row55)

typedef float v2f __attribute__((ext_vector_type(2)));

constexpr float cubic_c(float xin) {
    float x = xin < 0.0f ? -xin : xin;
    const float A = -0.75f;
    if (x <= 1.0f) return ((A + 2.0f) * x - (A + 3.0f)) * x * x + 1.0f;
    if (x < 2.0f)  return A * (((x - 5.0f) * x + 8.0f) * x - 4.0f);
    return 0.0f;
}

// X-pass: folded effective weights on contiguous window [s, s+3] (border clamp folded).
struct XTabT {
    float w[OUTS][4];
    int   s[OUTS];
    constexpr XTabT() : w{}, s{} {
        for (int o = 0; o < OUTS; ++o) {
            float src = ((float)o + 0.5f) * (56.0f / 96.0f) - 0.5f;
            int base = (int)src;
            if ((float)base > src) --base;
            int st = base - 1;
            if (st < 0) st = 0;
            if (st > HIN - 4) st = HIN - 4;
            s[o] = st;
            for (int q = 0; q < 4; ++q) {
                int tap = base - 1 + q;
                float wt = cubic_c(src - (float)tap);
                int p = tap < 0 ? 0 : (tap > HIN - 1 ? HIN - 1 : tap);
                w[o][p - st] += wt;
            }
        }
    }
};
constexpr XTabT XT;

// Y-pass: period-12 raw weights + relative tap start d (logical tap0 row = 7*(h/12)+d[h%12]).
// Border handled by replicated pad rows in tmp (validated: prior sessions absmax 0.0).
struct YTabT {
    float w[12][4];
    int   d[12];
    constexpr YTabT() : w{}, d{} {
        for (int ph = 0; ph < 12; ++ph) {
            float src = ((float)ph + 0.5f) * (56.0f / 96.0f) - 0.5f;
            int base = (int)src;
            if ((float)base > src) --base;
            d[ph] = base - 1;
            for (int q = 0; q < 4; ++q)
                w[ph][q] = cubic_c(src - (float)(base - 1 + q));
        }
    }
};
constexpr YTabT YT;

// Phase-1 window geometry per 16-col group G (verified against XT.s ranges, absmax 0.0):
//   G0: s in [0,7]   -> floats  0..11 (FS=0,  NF=3)
//   G1: s in [8,16]  -> floats  8..19 (FS=2,  NF=3)
//   G2: s in [17,26] -> floats 16..31 (FS=4,  NF=4)
//   G3: s in [26,35] -> floats 24..39 (FS=6,  NF=4)
//   G4: s in [36,44] -> floats 36..47 (FS=9,  NF=3)
//   G5: s in [45,52] -> floats 44..55 (FS=11, NF=3)
template<int G> struct P1G {
    static constexpr int FS = (G == 0) ? 0 : (G == 1) ? 2 : (G == 2) ? 4
                            : (G == 3) ? 6 : (G == 4) ? 9 : 11;
    static constexpr int NF = (G == 2 || G == 3) ? 4 : 3;
};

// ---- issue global loads for one row of BOTH maps into registers (prefetch) ----
template<int G>
__device__ __forceinline__ void p1_load(const float* __restrict__ r0,
                                        const float* __restrict__ r1,
                                        float4* __restrict__ pa,
                                        float4* __restrict__ pb) {
    const float4* A = (const float4*)r0 + P1G<G>::FS;
    const float4* B = (const float4*)r1 + P1G<G>::FS;
#pragma unroll
    for (int i = 0; i < P1G<G>::NF; ++i) { pa[i] = A[i]; pb[i] = B[i]; }
}

// ---- consume prefetched regs: repack + folded-weight FMA chain + ds_write ----
template<int G>
__device__ __forceinline__ void p1_comp(const float4* __restrict__ pa,
                                        const float4* __restrict__ pb,
                                        v2f* __restrict__ dst) {
    constexpr int FS = P1G<G>::FS, NF = P1G<G>::NF;
    v2f rr[NF * 4];
#pragma unroll
    for (int i = 0; i < NF; ++i) {
        rr[4 * i + 0] = (v2f){pa[i].x, pb[i].x};
        rr[4 * i + 1] = (v2f){pa[i].y, pb[i].y};
        rr[4 * i + 2] = (v2f){pa[i].z, pb[i].z};
        rr[4 * i + 3] = (v2f){pa[i].w, pb[i].w};
    }
#pragma unroll
    for (int i = 0; i < 8; ++i) {
        const int o0 = 16 * G + 2 * i, o1 = o0 + 1;
        const int s0 = XT.s[o0] - 4 * FS, s1 = XT.s[o1] - 4 * FS;
        v2f a0 = rr[s0] * (v2f){XT.w[o0][0], XT.w[o0][0]};
        a0 = __builtin_elementwise_fma((v2f){XT.w[o0][1], XT.w[o0][1]}, rr[s0 + 1], a0);
        a0 = __builtin_elementwise_fma((v2f){XT.w[o0][2], XT.w[o0][2]}, rr[s0 + 2], a0);
        a0 = __builtin_elementwise_fma((v2f){XT.w[o0][3], XT.w[o0][3]}, rr[s0 + 3], a0);
        v2f a1 = rr[s1] * (v2f){XT.w[o1][0], XT.w[o1][0]};
        a1 = __builtin_elementwise_fma((v2f){XT.w[o1][1], XT.w[o1][1]}, rr[s1 + 1], a1);
        a1 = __builtin_elementwise_fma((v2f){XT.w[o1][2], XT.w[o1][2]}, rr[s1 + 2], a1);
        a1 = __builtin_elementwise_fma((v2f){XT.w[o1][3], XT.w[o1][3]}, rr[s1 + 3], a1);
        float4 st = {a0.x, a0.y, a1.x, a1.y};
        *(float4*)(dst + 2 * i) = st;               // ds_write_b128, 16B-aligned
    }
}

__device__ __forceinline__ void do_load(int g, const float* r0, const float* r1,
                                        float4* pa, float4* pb) {
    if      (g == 0) p1_load<0>(r0, r1, pa, pb);
    else if (g == 1) p1_load<1>(r0, r1, pa, pb);
    else if (g == 2) p1_load<2>(r0, r1, pa, pb);
    else if (g == 3) p1_load<3>(r0, r1, pa, pb);
    else if (g == 4) p1_load<4>(r0, r1, pa, pb);
    else             p1_load<5>(r0, r1, pa, pb);
}

__device__ __forceinline__ void do_comp(int g, const float4* pa, const float4* pb, v2f* dst) {
    if      (g == 0) p1_comp<0>(pa, pb, dst);
    else if (g == 1) p1_comp<1>(pa, pb, dst);
    else if (g == 2) p1_comp<2>(pa, pb, dst);
    else if (g == 3) p1_comp<3>(pa, pb, dst);
    else if (g == 4) p1_comp<4>(pa, pb, dst);
    else             p1_comp<5>(pa, pb, dst);
}

// ---- y-value for (col pair, hh within quarter): quarter q covers out rows 24q..24q+23;
// c[] base = phys row 14q, so relative tap0 = 7*(hh/12) + d[hh%12] + 2 in [0,14]; +3 -> c[18].
// Bit-identical chain used by scan and rescan.
__device__ __forceinline__ v2f yv(const v2f* __restrict__ c, int hh) {
    const int ph = hh % 12, bb = hh / 12;
    const int i0 = 7 * bb + YT.d[ph] + 2;           // const after unroll
    v2f acc = c[i0] * (v2f){YT.w[ph][0], YT.w[ph][0]};
    acc = __builtin_elementwise_fma((v2f){YT.w[ph][1], YT.w[ph][1]}, c[i0 + 1], acc);
    acc = __builtin_elementwise_fma((v2f){YT.w[ph][2], YT.w[ph][2]}, c[i0 + 2], acc);
    acc = __builtin_elementwise_fma((v2f){YT.w[ph][3], YT.w[ph][3]}, c[i0 + 3], acc);
    return acc;
}

__global__ __launch_bounds__(NT)
void _Keypointer_kernel(const float* __restrict__ masks,
                        const float* __restrict__ boxes,
                        float* __restrict__ out) {
    __shared__ __align__(16) v2f tmp[TROWS * RST];  // 47,040 B
    __shared__ v2f wmax[6];
    __shared__ int candp[2];

    const int t   = threadIdx.x;
    const int g   = t >> 6;                         // col group (wave-uniform, 0..5)
    const int w   = t & 63;

    const int srcrow = min(max(w - 2, 0), HIN - 1);
    const int phys   = min(w, TROWS - 1);           // lanes 60..63 dup lane 59 (same data)
    v2f* dst = tmp + phys * RST + 16 * g;

    float4 pa[4], pb[4];                            // prefetch regs (static indexing only)

    int pair = blockIdx.x;
    {   // cold load for first pair
        const float* r0 = masks + (size_t)(2 * pair) * (HIN * WIN) + srcrow * WIN;
        do_load(g, r0, r0 + HIN * WIN, pa, pb);
    }

    for (int it = 0; it < ITERS; ++it) {
        const int bm0 = 2 * pair;
        const int nxt = pair + GRID;

        if (t == 0) { candp[0] = 0x7fffffff; candp[1] = 0x7fffffff; }

        // phase 1: consume prefetched regs (vmcnt wait happens here), write tmp
        do_comp(g, pa, pb, dst);

        // issue NEXT pair's loads now — they fly across the barriers & phase 2
        if (it + 1 < ITERS) {
            const float* r0 = masks + (size_t)(2 * nxt) * (HIN * WIN) + srcrow * WIN;
            do_load(g, r0, r0 + HIN * WIN, pa, pb);
        }
        __syncthreads();

        // ---- phase 2: thread = (col, row-quarter), both maps packed in v2f ----
        const int q    = t / 96;                    // 0..3
        const int col  = t - 96 * q;
        const int h0   = 24 * q;
        const v2f* cb  = tmp + (14 * q) * RST + col;
        v2f c[18];
#pragma unroll
        for (int i = 0; i < 18; ++i) c[i] = cb[i * RST];   // ds_read_b64, imm offsets

        v2f vmax = {-INFINITY, -INFINITY};
#pragma unroll
        for (int hh = 0; hh < 24; ++hh)
            vmax = __builtin_elementwise_max(vmax, yv(c, hh));

        // block max per map (per-wave shuffle tree, then 6-entry LDS combine)
        float m0 = vmax.x, m1 = vmax.y;
#pragma unroll
        for (int off = 32; off > 0; off >>= 1) {
            m0 = fmaxf(m0, __shfl_down(m0, off, 64));
            m1 = fmaxf(m1, __shfl_down(m1, off, 64));
        }
        if (w == 0) wmax[g] = (v2f){m0, m1};
        __syncthreads();

        const float M0 = fmaxf(fmaxf(fmaxf(wmax[0].x, wmax[1].x), fmaxf(wmax[2].x, wmax[3].x)),
                               fmaxf(wmax[4].x, wmax[5].x));
        const float M1 = fmaxf(fmaxf(fmaxf(wmax[0].y, wmax[1].y), fmaxf(wmax[2].y, wmax[3].y)),
                               fmaxf(wmax[4].y, wmax[5].y));

        // sparse rescan: only threads whose (col, quarter) contained the max participate
        if (vmax.x == M0 || vmax.y == M1) {
            int c0 = 0x7fffffff, c1 = 0x7fffffff;
#pragma unroll
            for (int hh = 0; hh < 24; ++hh) {
                v2f a = yv(c, hh);                  // bit-identical recompute
                int fp = (h0 + hh) * OUTS + col;
                if (a.x == M0) c0 = min(c0, fp);
                if (a.y == M1) c1 = min(c1, fp);
            }
            if (c0 != 0x7fffffff) atomicMin(&candp[0], c0);
            if (c1 != 0x7fffffff) atomicMin(&candp[1], c1);
        }
        __syncthreads();

        if (t < 2) {
            const int map = bm0 + t;
            const float M = t ? M1 : M0;
            const int bp  = candp[t];
            const int r = map / K_, k = map - r * K_;
            const int y = bp / OUTS, x = bp - y * OUTS;
            const float b0f = boxes[r * 4 + 0], b1f = boxes[r * 4 + 1];
            const float b2f = boxes[r * 4 + 2], b3f = boxes[r * 4 + 3];
            const float corr0 = fmaxf(b2f - b0f, 1.0f) / (float)OUTS;
            const float corr1 = fmaxf(b3f - b1f, 1.0f) / (float)OUTS;
            const float p0 = ((float)y + 0.5f) * corr0 + b0f;
            const float p1 = ((float)x + 0.5f) * corr1 + b1f;
            out[(r * 3 + 0) * K_ + k] = p0;
            out[(r * 3 + 1) * K_ + k] = p1;
            out[(r * 3 + 2) * K_ + k] = 1.0f;
            out[R_ * 3 * K_ + r * K_ + k] = M;
        }
        __syncthreads();   // protect tmp/wmax/candp before next iteration overwrites
        pair = nxt;
    }
}

extern "C" void kernel_launch(void* const* d_in, const int* in_sizes, int n_in,
                              void* d_out, int out_size, void* d_ws, size_t ws_size,
                              hipStream_t stream) {
    const float* masks = (const float*)d_in[0];
    const float* boxes = (const float*)d_in[1];
    float* out = (float*)d_out;
    _Keypointer_kernel<<<GRID, NT, 0, stream>>>(masks, boxes, out);
}

// Round 6
// 180.757 us; speedup vs baseline: 1.3392x; 1.3392x over previous
//
#include <hip/hip_runtime.h>

#define R_    512
#define K_    17
#define HIN   56
#define WIN   56
#define OUTS  96
#define NMAP  (R_ * K_)
#define NT    64      // ONE wave per block: no __syncthreads anywhere
#define GRID  (NMAP / 2)
#define WST   18      // strip row stride in v2f units (144 B: 16B-aligned, 4-bank stagger)
#define TROWS 60      // phys rows: 0,1 = pad(row0); 2..57 = rows 0..55; 58,59 = pad(row55)

typedef float v2f __attribute__((ext_vector_type(2)));

// LDS fence: pin scheduling on both sides of the waitcnt (guide rule #18 — hipcc
// can move ops across a bare inline-asm waitcnt; sched_barrier(0) is the fix).
#define LDS_FENCE() do {                                      \
        __builtin_amdgcn_sched_barrier(0);                    \
        asm volatile("s_waitcnt lgkmcnt(0)" ::: "memory");    \
        __builtin_amdgcn_sched_barrier(0);                    \
    } while (0)

constexpr float cubic_c(float xin) {
    float x = xin < 0.0f ? -xin : xin;
    const float A = -0.75f;
    if (x <= 1.0f) return ((A + 2.0f) * x - (A + 3.0f)) * x * x + 1.0f;
    if (x < 2.0f)  return A * (((x - 5.0f) * x + 8.0f) * x - 4.0f);
    return 0.0f;
}

// X-pass: folded effective weights on contiguous window [s, s+3] (border clamp folded).
struct XTabT {
    float w[OUTS][4];
    int   s[OUTS];
    constexpr XTabT() : w{}, s{} {
        for (int o = 0; o < OUTS; ++o) {
            float src = ((float)o + 0.5f) * (56.0f / 96.0f) - 0.5f;
            int base = (int)src;
            if ((float)base > src) --base;
            int st = base - 1;
            if (st < 0) st = 0;
            if (st > HIN - 4) st = HIN - 4;
            s[o] = st;
            for (int q = 0; q < 4; ++q) {
                int tap = base - 1 + q;
                float wt = cubic_c(src - (float)tap);
                int p = tap < 0 ? 0 : (tap > HIN - 1 ? HIN - 1 : tap);
                w[o][p - st] += wt;
            }
        }
    }
};
constexpr XTabT XT;

// Y-pass: period-12 raw weights + relative tap start d (logical tap0 row = 7*(h/12)+d[h%12]).
// Border handled by replicated pad rows in tmp (validated: prior sessions absmax 0.0).
struct YTabT {
    float w[12][4];
    int   d[12];
    constexpr YTabT() : w{}, d{} {
        for (int ph = 0; ph < 12; ++ph) {
            float src = ((float)ph + 0.5f) * (56.0f / 96.0f) - 0.5f;
            int base = (int)src;
            if ((float)base > src) --base;
            d[ph] = base - 1;
            for (int q = 0; q < 4; ++q)
                w[ph][q] = cubic_c(src - (float)(base - 1 + q));
        }
    }
};
constexpr YTabT YT;

// 16-col strips, uniform 4-float4 windows (re-verified against XT.s ranges:
//   G0: s in [0,7]   need [0,10]  FS=0  win [0,15]
//   G1: s in [8,16]  need [8,19]  FS=1  win [4,19]
//   G2: s in [17,26] need [17,29] FS=4  win [16,31]
//   G3: s in [26,35] need [26,38] FS=6  win [24,39]
//   G4: s in [36,44] need [36,47] FS=8  win [32,47]
//   G5: s in [45,52] need [45,55] FS=10 win [40,55])
template<int G> struct FSv {
    static constexpr int v = (G == 0) ? 0 : (G == 1) ? 1 : (G == 2) ? 4
                           : (G == 3) ? 6 : (G == 4) ? 8 : 10;
};

// ---- y-value for (col, hh within quarter): quarter q covers out rows 24q..24q+23;
// c[] base = phys row 14q, so relative tap0 = 7*(hh/12) + d[hh%12] + 2 in [0,14]; +3 -> c[18].
__device__ __forceinline__ v2f yv(const v2f* c, int hh) {
    const int ph = hh % 12, bb = hh / 12;
    const int i0 = 7 * bb + YT.d[ph] + 2;           // const after unroll
    v2f acc = c[i0] * (v2f){YT.w[ph][0], YT.w[ph][0]};
    acc = __builtin_elementwise_fma((v2f){YT.w[ph][1], YT.w[ph][1]}, c[i0 + 1], acc);
    acc = __builtin_elementwise_fma((v2f){YT.w[ph][2], YT.w[ph][2]}, c[i0 + 2], acc);
    acc = __builtin_elementwise_fma((v2f){YT.w[ph][3], YT.w[ph][3]}, c[i0 + 3], acc);
    return acc;
}

// ---- one 16-col strip, entirely wave-internal ----
// NOTE: wrow/crd alias the same LDS buffer by design — NO __restrict__ here
// (R4 bug: false restrict licensed the compiler to break the write->read order).
template<int G>
__device__ __forceinline__ void strip_comp(float4 a0, float4 a1, float4 a2, float4 a3,
                                           float4 b0, float4 b1, float4 b2, float4 b3,
                                           v2f* wrow,       // tmp + phys*WST
                                           const v2f* crd,  // tmp + 14q*WST + cc
                                           int pbase,       // 24q*96 + cc
                                           float& m0, int& p0, float& m1, int& p1) {
    constexpr int FS = FSv<G>::v;
    v2f rr[16];
    rr[0]  = (v2f){a0.x, b0.x}; rr[1]  = (v2f){a0.y, b0.y};
    rr[2]  = (v2f){a0.z, b0.z}; rr[3]  = (v2f){a0.w, b0.w};
    rr[4]  = (v2f){a1.x, b1.x}; rr[5]  = (v2f){a1.y, b1.y};
    rr[6]  = (v2f){a1.z, b1.z}; rr[7]  = (v2f){a1.w, b1.w};
    rr[8]  = (v2f){a2.x, b2.x}; rr[9]  = (v2f){a2.y, b2.y};
    rr[10] = (v2f){a2.z, b2.z}; rr[11] = (v2f){a2.w, b2.w};
    rr[12] = (v2f){a3.x, b3.x}; rr[13] = (v2f){a3.y, b3.y};
    rr[14] = (v2f){a3.z, b3.z}; rr[15] = (v2f){a3.w, b3.w};

    // WAR fence: previous strip's ds_reads retired before we overwrite the buffer.
    LDS_FENCE();
#pragma unroll
    for (int i = 0; i < 8; ++i) {
        const int o0 = 16 * G + 2 * i, o1 = o0 + 1;
        const int s0 = XT.s[o0] - 4 * FS, s1 = XT.s[o1] - 4 * FS;  // compile-time, in [0,12]
        v2f x0 = rr[s0] * (v2f){XT.w[o0][0], XT.w[o0][0]};
        x0 = __builtin_elementwise_fma((v2f){XT.w[o0][1], XT.w[o0][1]}, rr[s0 + 1], x0);
        x0 = __builtin_elementwise_fma((v2f){XT.w[o0][2], XT.w[o0][2]}, rr[s0 + 2], x0);
        x0 = __builtin_elementwise_fma((v2f){XT.w[o0][3], XT.w[o0][3]}, rr[s0 + 3], x0);
        v2f x1 = rr[s1] * (v2f){XT.w[o1][0], XT.w[o1][0]};
        x1 = __builtin_elementwise_fma((v2f){XT.w[o1][1], XT.w[o1][1]}, rr[s1 + 1], x1);
        x1 = __builtin_elementwise_fma((v2f){XT.w[o1][2], XT.w[o1][2]}, rr[s1 + 2], x1);
        x1 = __builtin_elementwise_fma((v2f){XT.w[o1][3], XT.w[o1][3]}, rr[s1 + 3], x1);
        float4 st = {x0.x, x0.y, x1.x, x1.y};
        *(float4*)(wrow + 2 * i) = st;              // ds_write_b128, (phys*18+2i) even -> 16B ok
    }
    // RAW fence: ds_write is wave-wide; lgkmcnt(0) retires all lanes' writes before reads.
    LDS_FENCE();

    v2f c[18];
#pragma unroll
    for (int i = 0; i < 18; ++i) c[i] = crd[i * WST];  // ds_read_b64, imm offsets

    v2f sv = {-INFINITY, -INFINITY};
    int h0i = 0, h1i = 0;
#pragma unroll
    for (int hh = 0; hh < 24; ++hh) {
        v2f a = yv(c, hh);
        if (a.x > sv.x) { sv.x = a.x; h0i = hh; }   // strict > : first (min-fp) within strip
        if (a.y > sv.y) { sv.y = a.y; h1i = hh; }
    }
    const int fp0 = pbase + 16 * G + h0i * 96;
    const int fp1 = pbase + 16 * G + h1i * 96;
    if (sv.x > m0 || (sv.x == m0 && fp0 < p0)) { m0 = sv.x; p0 = fp0; }
    if (sv.y > m1 || (sv.y == m1 && fp1 < p1)) { m1 = sv.y; p1 = fp1; }
}

__global__ __launch_bounds__(NT)
void _Keypointer_kernel(const float* __restrict__ masks,
                        const float* __restrict__ boxes,
                        float* __restrict__ out) {
    __shared__ __align__(16) v2f tmp[TROWS * WST];  // 8,640 B — wave-private

    const int w   = threadIdx.x;                    // 0..63, one wave
    const int bm0 = 2 * blockIdx.x;

    // phase-1 role: lane = phys row (pads replicated; lanes 60..63 dup phys 59, same data)
    const int srcrow = min(max(w - 2, 0), HIN - 1);
    const int phys   = min(w, TROWS - 1);
    const float* r0 = masks + (size_t)bm0 * (HIN * WIN) + srcrow * WIN;
    const float* r1 = r0 + HIN * WIN;
    v2f* wrow = tmp + phys * WST;

    // phase-2 role: lane = (col-in-strip, row-quarter); 16x4 = 64, bijective
    const int cc = w & 15, q = w >> 4;
    const v2f* crd = tmp + (14 * q) * WST + cc;
    const int pbase = (24 * q) * OUTS + cc;

    float m0 = -INFINITY, m1 = -INFINITY;
    int   p0 = 0x7fffffff, p1 = 0x7fffffff;

    float4 A0, A1, A2, A3, B0, B1, B2, B3;          // named regs only (R3 lesson:
    float4 C0, C1, C2, C3, D0, D1, D2, D3;          // arrays across branches -> scratch)

#define LOADS(FS_, X0, X1, X2, X3, Y0, Y1, Y2, Y3) {            \
        const float4* _A = (const float4*)r0 + (FS_);           \
        const float4* _B = (const float4*)r1 + (FS_);           \
        X0 = _A[0]; X1 = _A[1]; X2 = _A[2]; X3 = _A[3];         \
        Y0 = _B[0]; Y1 = _B[1]; Y2 = _B[2]; Y3 = _B[3]; }

    // software pipeline: each strip's loads issued >=1 strip before consumption;
    // compiler emits counted vmcnt waits, so next loads stay in flight during comp.
    LOADS(0,  A0, A1, A2, A3, B0, B1, B2, B3)
    LOADS(1,  C0, C1, C2, C3, D0, D1, D2, D3)
    strip_comp<0>(A0, A1, A2, A3, B0, B1, B2, B3, wrow, crd, pbase, m0, p0, m1, p1);
    LOADS(4,  A0, A1, A2, A3, B0, B1, B2, B3)
    strip_comp<1>(C0, C1, C2, C3, D0, D1, D2, D3, wrow, crd, pbase, m0, p0, m1, p1);
    LOADS(6,  C0, C1, C2, C3, D0, D1, D2, D3)
    strip_comp<2>(A0, A1, A2, A3, B0, B1, B2, B3, wrow, crd, pbase, m0, p0, m1, p1);
    LOADS(8,  A0, A1, A2, A3, B0, B1, B2, B3)
    strip_comp<3>(C0, C1, C2, C3, D0, D1, D2, D3, wrow, crd, pbase, m0, p0, m1, p1);
    LOADS(10, C0, C1, C2, C3, D0, D1, D2, D3)
    strip_comp<4>(A0, A1, A2, A3, B0, B1, B2, B3, wrow, crd, pbase, m0, p0, m1, p1);
    strip_comp<5>(C0, C1, C2, C3, D0, D1, D2, D3, wrow, crd, pbase, m0, p0, m1, p1);
#undef LOADS

    // wave argmax reduce: max value, min flat-pos on ties (== jnp.argmax first-occurrence)
#pragma unroll
    for (int off = 32; off; off >>= 1) {
        float t0 = __shfl_xor(m0, off, 64); int u0 = __shfl_xor(p0, off, 64);
        if (t0 > m0 || (t0 == m0 && u0 < p0)) { m0 = t0; p0 = u0; }
        float t1 = __shfl_xor(m1, off, 64); int u1 = __shfl_xor(p1, off, 64);
        if (t1 > m1 || (t1 == m1 && u1 < p1)) { m1 = t1; p1 = u1; }
    }

    if (w == 0) {
#pragma unroll
        for (int mi = 0; mi < 2; ++mi) {
            const int map = bm0 + mi;
            const float M = mi ? m1 : m0;
            const int bp  = mi ? p1 : p0;
            const int r = map / K_, k = map - r * K_;
            const int y = bp / OUTS, x = bp - y * OUTS;
            const float b0f = boxes[r * 4 + 0], b1f = boxes[r * 4 + 1];
            const float b2f = boxes[r * 4 + 2], b3f = boxes[r * 4 + 3];
            const float corr0 = fmaxf(b2f - b0f, 1.0f) / (float)OUTS;
            const float corr1 = fmaxf(b3f - b1f, 1.0f) / (float)OUTS;
            const float pp0 = ((float)y + 0.5f) * corr0 + b0f;
            const float pp1 = ((float)x + 0.5f) * corr1 + b1f;
            out[(r * 3 + 0) * K_ + k] = pp0;
            out[(r * 3 + 1) * K_ + k] = pp1;
            out[(r * 3 + 2) * K_ + k] = 1.0f;
            out[R_ * 3 * K_ + r * K_ + k] = M;
        }
    }
}

extern "C" void kernel_launch(void* const* d_in, const int* in_sizes, int n_in,
                              void* d_out, int out_size, void* d_ws, size_t ws_size,
                              hipStream_t stream) {
    const float* masks = (const float*)d_in[0];
    const float* boxes = (const float*)d_in[1];
    float* out = (float*)d_out;
    _Keypointer_kernel<<<GRID, NT, 0, stream>>>(masks, boxes, out);
}